// Round 4
// baseline (150.578 us; speedup 1.0000x reference)
//
#include <hip/hip_runtime.h>

// CIN restructured:
//   out1[b,h] = sum_d h1[b,h,d];   h1[b,h,d] = sum_{f,q} W0[h,fq] x[b,f,d] x[b,q,d]
//   out2[b,h] = sum_p W1[h,p] U[b,p];  U[b,(f,q)] = sum_d x[b,f,d] h1[b,q,d]
// (d-contraction first: layer2 drops 41.9 GF -> 2.9 GF total.)
// phaseA (256 blk x 512 thr, 1/CU): layer1 K-loop (G=8 batches, W0-frag stream
//   from L2 at 26 B/cyc/CU), h1 in LDS, U via tiny MFMAs -> ws (bf16).
// phaseB (256 blk x 256 thr): out2 GEMM, b-tile 64 x k-slice 8, atomicAdd fp32.

#define F0   39
#define D_   16
#define H_   128
#define P0_  1521
#define P1_  4992
#define G8   8
#define NF1  (F0 * 2 * 8)   // 624 layer-1 A-frags
#define NF2  (F0 * 4 * 8)   // 1248 W1 A-frags

typedef __attribute__((ext_vector_type(8))) short   short8;
typedef __attribute__((ext_vector_type(8))) __bf16  bf16x8;
typedef __attribute__((ext_vector_type(4))) float   floatx4;

__device__ __forceinline__ unsigned short bf16rne(float f) {
  unsigned int u = __float_as_uint(f);
  u += 0x7FFFu + ((u >> 16) & 1u);
  return (unsigned short)(u >> 16);
}

__device__ __forceinline__ floatx4 mfma16(short8 a, short8 b, floatx4 c) {
  return __builtin_amdgcn_mfma_f32_16x16x32_bf16(
      __builtin_bit_cast(bf16x8, a), __builtin_bit_cast(bf16x8, b), c, 0, 0, 0);
}

// ---------- pack W into MFMA A-frag order (verified layout, R3) ----------
__global__ __launch_bounds__(256) void pack_w_kernel(const float* __restrict__ w0,
                                                     const float* __restrict__ w1,
                                                     short8* __restrict__ wA1,
                                                     short8* __restrict__ wA2) {
  int id = blockIdx.x * 256 + threadIdx.x;
  union { short8 v; unsigned short e[8]; } pk;
  if (id < NF1 * 64) {
    int lane = id & 63, frag = id >> 6;
    int t = frag & 7, s = (frag >> 3) & 1, f = frag >> 4;
    int m = t * 16 + (lane & 15);
    int qb = s * 32 + (lane >> 4) * 8;
#pragma unroll
    for (int j = 0; j < 8; ++j) {
      int q = qb + j;
      float v = (q < F0) ? w0[(size_t)m * P0_ + f * F0 + q] : 0.f;
      pk.e[j] = bf16rne(v);
    }
    wA1[frag * 64 + lane] = pk.v;
  } else if (id < (NF1 + NF2) * 64) {
    int u = id - NF1 * 64;
    int lane = u & 63, frag = u >> 6;
    int t = frag & 7, s = (frag >> 3) & 3, f = frag >> 5;
    int m = t * 16 + (lane & 15);
    int pb = f * 128 + s * 32 + (lane >> 4) * 8;
#pragma unroll
    for (int j = 0; j < 8; ++j) pk.e[j] = bf16rne(w1[(size_t)m * P1_ + pb + j]);
    wA2[frag * 64 + lane] = pk.v;
  }
}

// ---------- phase A: h1 + out1 + U ----------
__global__ __launch_bounds__(512, 2) void cin_phaseA(const float* __restrict__ x,
                                                     const short8* __restrict__ wA1,
                                                     float* __restrict__ out,
                                                     unsigned short* __restrict__ U) {
  __shared__ __align__(16) float xs[G8][F0][D_];                  // 19.9 KB
  __shared__ __align__(16) unsigned short xTb[G8 * 8 * D_ * 8];   // 16 KB
  __shared__ __align__(16) float S[H_][G8 * D_ + 4];              // 67.6 KB [128][132]

  const int tid  = threadIdx.x;
  const int lane = tid & 63;
  const int wv   = tid >> 6;      // 8 waves; wave = m-tile t
  const int t    = wv;
  const int col  = lane & 15;
  const int quad = lane >> 4;
  const int b0   = blockIdx.x * G8;
  const floatx4 zf4 = {0.f, 0.f, 0.f, 0.f};

  // stage x (coalesced float4)
  {
    const float4* xg = (const float4*)(x + (size_t)b0 * (F0 * D_));
    float4* xl = (float4*)xs;
    for (int i = tid; i < G8 * F0 * D_ / 4; i += 512) xl[i] = xg[i];
  }
  __syncthreads();

  // xTb[g][q8][d][j] = bf16(x[g][q8*8+j][d]), zero-pad q>=39
  for (int i = tid; i < G8 * 8 * D_; i += 512) {
    int d = i & 15, q8 = (i >> 4) & 7, g = i >> 7;
    union { short8 v; unsigned short e[8]; } pk;
#pragma unroll
    for (int j = 0; j < 8; ++j) {
      int q = q8 * 8 + j;
      pk.e[j] = (q < F0) ? bf16rne(xs[g][q][d]) : (unsigned short)0;
    }
    *(short8*)&xTb[(size_t)i * 8] = pk.v;
  }
  __syncthreads();

  // layer-1 B-frags (f-invariant)
  short8 bx[2][G8];
#pragma unroll
  for (int s = 0; s < 2; ++s)
#pragma unroll
    for (int g = 0; g < G8; ++g)
      bx[s][g] = *(const short8*)&xTb[(size_t)(((g * 8 + s * 4 + quad) * 16) + col) * 8];

  floatx4 acc2[G8];
#pragma unroll
  for (int g = 0; g < G8; ++g) acc2[g] = zf4;

  // ===== layer 1: f-loop, double-buffered A-frags from L2 =====
  short8 a0 = wA1[(size_t)((0 * 2 + 0) * 8 + t) * 64 + lane];
  short8 a1 = wA1[(size_t)((0 * 2 + 1) * 8 + t) * 64 + lane];
  for (int f = 0; f < F0; ++f) {
    int fn = (f + 1 < F0) ? f + 1 : f;
    short8 na0 = wA1[(size_t)((fn * 2 + 0) * 8 + t) * 64 + lane];
    short8 na1 = wA1[(size_t)((fn * 2 + 1) * 8 + t) * 64 + lane];
    float sx[G8];
#pragma unroll
    for (int g = 0; g < G8; ++g) sx[g] = xs[g][f][col];
#pragma unroll
    for (int g = 0; g < G8; ++g) {
      floatx4 acf = mfma16(a0, bx[0][g], zf4);
      acf = mfma16(a1, bx[1][g], acf);
#pragma unroll
      for (int r = 0; r < 4; ++r) acc2[g][r] += acf[r] * sx[g];
    }
    a0 = na0; a1 = na1;
  }

  // stage h1 fp32 into S
#pragma unroll
  for (int g = 0; g < G8; ++g)
#pragma unroll
    for (int r = 0; r < 4; ++r)
      S[t * 16 + quad * 4 + r][g * 16 + col] = acc2[g][r];
  __syncthreads();

  // out1[b,h] = sum_d h1
  for (int i = tid; i < G8 * H_; i += 512) {
    int h = i & 127, g = i >> 7;
    const float4* sp = (const float4*)&S[h][g * 16];
    float4 v0 = sp[0], v1 = sp[1], v2 = sp[2], v3 = sp[3];
    out[(size_t)(b0 + g) * 256 + h] =
        (v0.x + v0.y + v0.z + v0.w) + (v1.x + v1.y + v1.z + v1.w) +
        (v2.x + v2.y + v2.z + v2.w) + (v3.x + v3.y + v3.z + v3.w);
  }

  // ===== U[b,(f,q)] = sum_d x[b,f,d] h1[b,q,d]  (wave g = wv) =====
  {
    const int g = wv;
    short8 af[3];
#pragma unroll
    for (int ft = 0; ft < 3; ++ft) {
      union { short8 v; unsigned short e[8]; } pk;
      int f = ft * 16 + col;
      if (quad < 2 && f < F0) {
        const float* xp = &xs[g][f][quad * 8];
#pragma unroll
        for (int j = 0; j < 8; ++j) pk.e[j] = bf16rne(xp[j]);
      } else {
#pragma unroll
        for (int j = 0; j < 8; ++j) pk.e[j] = 0;
      }
      af[ft] = pk.v;
    }
#pragma unroll
    for (int qt = 0; qt < 8; ++qt) {
      union { short8 v; unsigned short e[8]; } pk;
      if (quad < 2) {
        const float* sp = &S[qt * 16 + col][g * 16 + quad * 8];
#pragma unroll
        for (int j = 0; j < 8; ++j) pk.e[j] = bf16rne(sp[j]);
      } else {
#pragma unroll
        for (int j = 0; j < 8; ++j) pk.e[j] = 0;
      }
      short8 bq = pk.v;
#pragma unroll
      for (int ft = 0; ft < 3; ++ft) {
        floatx4 c = mfma16(af[ft], bq, zf4);
#pragma unroll
        for (int r = 0; r < 4; ++r) {
          int f = ft * 16 + quad * 4 + r;
          if (f < F0)
            U[(size_t)(b0 + g) * P1_ + f * H_ + qt * 16 + col] = bf16rne(c[r]);
        }
      }
    }
  }
}

// ---------- phase B: out2[b,h] += sum_p W1[h,p] U[b,p] ----------
// grid 256 = 32 b-tiles(64) x 8 k-slices; block 256 thr = 4 waves (mh x kh)
__global__ __launch_bounds__(256, 4) void cin_phaseB(const unsigned short* __restrict__ U,
                                                     const short8* __restrict__ wA2,
                                                     float* __restrict__ out) {
  const int tid  = threadIdx.x;
  const int lane = tid & 63;
  const int wv   = tid >> 6;
  const int mh   = wv >> 1;     // m-half: tiles mh*4..mh*4+3
  const int kh   = wv & 1;      // k interleave within slice
  const int col  = lane & 15;
  const int quad = lane >> 4;
  const int bt   = blockIdx.x >> 3;
  const int ks   = blockIdx.x & 7;
  const int bb0  = bt * 64;
  const int c0   = (ks < 4) ? ks * 20 : 80 + (ks - 4) * 19;
  const int len  = (ks < 4) ? 20 : 19;
  const floatx4 zf4 = {0.f, 0.f, 0.f, 0.f};

  floatx4 acc[4][4];   // [m-tile i][n-tile nt]
#pragma unroll
  for (int i = 0; i < 4; ++i)
#pragma unroll
    for (int nt = 0; nt < 4; ++nt) acc[i][nt] = zf4;

  for (int ci = kh; ci < len; ci += 2) {
    int c = c0 + ci;
    short8 a[4], b[4];
#pragma unroll
    for (int i = 0; i < 4; ++i)
      a[i] = wA2[(size_t)(c * 8 + mh * 4 + i) * 64 + lane];
#pragma unroll
    for (int nt = 0; nt < 4; ++nt)
      b[nt] = *(const short8*)(U + (size_t)(bb0 + nt * 16 + col) * P1_ + c * 32 + quad * 8);
#pragma unroll
    for (int i = 0; i < 4; ++i)
#pragma unroll
      for (int nt = 0; nt < 4; ++nt) acc[i][nt] = mfma16(a[i], b[nt], acc[i][nt]);
  }

#pragma unroll
  for (int i = 0; i < 4; ++i)
#pragma unroll
    for (int nt = 0; nt < 4; ++nt)
#pragma unroll
      for (int r = 0; r < 4; ++r) {
        int h = (mh * 4 + i) * 16 + quad * 4 + r;
        int b = bb0 + nt * 16 + col;
        atomicAdd(&out[(size_t)b * 256 + 128 + h], acc[i][nt][r]);
      }
}

// ---------- mid fallback: R3 G=4 kernel (known-good, needs only wA) ----------
__global__ __launch_bounds__(256, 2) void cin_mfma_g4(const float* __restrict__ x,
                                                      const short8* __restrict__ wA1,
                                                      const short8* __restrict__ wA2,
                                                      float* __restrict__ out) {
  __shared__ __align__(16) float xs[4][F0][D_];
  __shared__ __align__(16) unsigned short xTb[4 * 8 * D_ * 8];
  __shared__ __align__(16) unsigned short hTb[4 * 16 * D_ * 8];
  __shared__ __align__(16) float S[H_][4 * D_ + 4];

  const int tid  = threadIdx.x;
  const int lane = tid & 63;
  const int wv   = tid >> 6;
  const int t0   = wv * 2;
  const int col  = lane & 15;
  const int quad = lane >> 4;
  const int b0   = blockIdx.x * 4;
  const floatx4 zf4 = {0.f, 0.f, 0.f, 0.f};

  {
    const float4* xg = (const float4*)(x + (size_t)b0 * (F0 * D_));
    float4* xl = (float4*)xs;
    for (int i = tid; i < 4 * F0 * D_ / 4; i += 256) xl[i] = xg[i];
  }
  __syncthreads();
  for (int i = tid; i < 4 * 8 * D_; i += 256) {
    int d = i & 15, q8 = (i >> 4) & 7, g = i >> 7;
    union { short8 v; unsigned short e[8]; } pk;
#pragma unroll
    for (int j = 0; j < 8; ++j) {
      int q = q8 * 8 + j;
      pk.e[j] = (q < F0) ? bf16rne(xs[g][q][d]) : (unsigned short)0;
    }
    *(short8*)&xTb[(size_t)i * 8] = pk.v;
  }
  __syncthreads();
  short8 bx[2][4];
#pragma unroll
  for (int s = 0; s < 2; ++s)
#pragma unroll
    for (int g = 0; g < 4; ++g)
      bx[s][g] = *(const short8*)&xTb[(size_t)(((g * 8 + s * 4 + quad) * 16) + col) * 8];
  floatx4 acc2[2][4];
#pragma unroll
  for (int tt = 0; tt < 2; ++tt)
#pragma unroll
    for (int g = 0; g < 4; ++g) acc2[tt][g] = zf4;
  for (int f = 0; f < F0; ++f) {
    short8 a[2][2];
#pragma unroll
    for (int s = 0; s < 2; ++s)
#pragma unroll
      for (int tt = 0; tt < 2; ++tt)
        a[s][tt] = wA1[(size_t)((f * 2 + s) * 8 + t0 + tt) * 64 + lane];
    float sx[4];
#pragma unroll
    for (int g = 0; g < 4; ++g) sx[g] = xs[g][f][col];
#pragma unroll
    for (int tt = 0; tt < 2; ++tt)
#pragma unroll
      for (int g = 0; g < 4; ++g) {
        floatx4 acf = mfma16(a[0][tt], bx[0][g], zf4);
        acf = mfma16(a[1][tt], bx[1][g], acf);
#pragma unroll
        for (int r = 0; r < 4; ++r) acc2[tt][g][r] += acf[r] * sx[g];
      }
  }
#pragma unroll
  for (int tt = 0; tt < 2; ++tt)
#pragma unroll
    for (int g = 0; g < 4; ++g)
#pragma unroll
      for (int r = 0; r < 4; ++r)
        S[(t0 + tt) * 16 + quad * 4 + r][g * 16 + col] = acc2[tt][g][r];
  __syncthreads();
  for (int i = tid; i < 4 * 16 * D_; i += 256) {
    int d = i & 15, q8 = (i >> 4) & 15, g = i >> 8;
    union { short8 v; unsigned short e[8]; } pk;
#pragma unroll
    for (int j = 0; j < 8; ++j) pk.e[j] = bf16rne(S[q8 * 8 + j][g * 16 + d]);
    *(short8*)&hTb[(size_t)i * 8] = pk.v;
  }
  for (int i = tid; i < 4 * H_; i += 256) {
    int h = i & 127, g = i >> 7;
    const float4* sp = (const float4*)&S[h][g * 16];
    float4 v0 = sp[0], v1 = sp[1], v2 = sp[2], v3 = sp[3];
    out[(size_t)(b0 + g) * 256 + h] =
        (v0.x + v0.y + v0.z + v0.w) + (v1.x + v1.y + v1.z + v1.w) +
        (v2.x + v2.y + v2.z + v2.w) + (v3.x + v3.y + v3.z + v3.w);
  }
  __syncthreads();
  short8 bh[4][4];
#pragma unroll
  for (int s = 0; s < 4; ++s)
#pragma unroll
    for (int g = 0; g < 4; ++g)
      bh[s][g] = *(const short8*)&hTb[(size_t)(((g * 16 + s * 4 + quad) * 16) + col) * 8];
#pragma unroll
  for (int tt = 0; tt < 2; ++tt)
#pragma unroll
    for (int g = 0; g < 4; ++g) acc2[tt][g] = zf4;
  for (int f = 0; f < F0; ++f) {
    short8 a[4][2];
#pragma unroll
    for (int s = 0; s < 4; ++s)
#pragma unroll
      for (int tt = 0; tt < 2; ++tt)
        a[s][tt] = wA2[(size_t)((f * 4 + s) * 8 + t0 + tt) * 64 + lane];
    float sx[4];
#pragma unroll
    for (int g = 0; g < 4; ++g) sx[g] = xs[g][f][col];
#pragma unroll
    for (int tt = 0; tt < 2; ++tt)
#pragma unroll
      for (int g = 0; g < 4; ++g) {
        floatx4 acf = mfma16(a[0][tt], bh[0][g], zf4);
        acf = mfma16(a[1][tt], bh[1][g], acf);
        acf = mfma16(a[2][tt], bh[2][g], acf);
        acf = mfma16(a[3][tt], bh[3][g], acf);
#pragma unroll
        for (int r = 0; r < 4; ++r) acc2[tt][g][r] += acf[r] * sx[g];
      }
  }
#pragma unroll
  for (int tt = 0; tt < 2; ++tt)
#pragma unroll
    for (int g = 0; g < 4; ++g)
#pragma unroll
      for (int r = 0; r < 4; ++r)
        S[(t0 + tt) * 16 + quad * 4 + r][g * 16 + col] = acc2[tt][g][r];
  __syncthreads();
  for (int i = tid; i < 4 * H_; i += 256) {
    int h = i & 127, g = i >> 7;
    const float4* sp = (const float4*)&S[h][g * 16];
    float4 v0 = sp[0], v1 = sp[1], v2 = sp[2], v3 = sp[3];
    out[(size_t)(b0 + g) * 256 + 128 + h] =
        (v0.x + v0.y + v0.z + v0.w) + (v1.x + v1.y + v1.z + v1.w) +
        (v2.x + v2.y + v2.z + v2.w) + (v3.x + v3.y + v3.z + v3.w);
  }
}

// ---------- fp32 last-resort fallback ----------
__global__ __launch_bounds__(128) void cin_fused_fallback(const float* __restrict__ x,
                                                          const float* __restrict__ w0,
                                                          const float* __restrict__ w1,
                                                          float* __restrict__ out) {
  __shared__ float4 xs4[F0 * D_ / 4];
  __shared__ float4 h1s4[H_ * D_ / 4];
  __shared__ float4 z4[H_ * D_ / 4];
  const int tid = threadIdx.x;
  const int b = blockIdx.x;
  const int hh = tid >> 2, dd = tid & 3, h0 = hh << 2;
  {
    const float4* xg = (const float4*)(x + (size_t)b * (F0 * D_));
    for (int i = tid; i < F0 * D_ / 4; i += 128) xs4[i] = xg[i];
  }
  __syncthreads();
  float acc[4][4];
#pragma unroll
  for (int i = 0; i < 4; ++i)
#pragma unroll
    for (int j = 0; j < 4; ++j) acc[i][j] = 0.f;
  for (int f = 0; f < F0; ++f) {
    for (int i = tid; i < F0 * D_ / 4; i += 128) {
      float4 xv = xs4[(f << 2) + (i & 3)], qv = xs4[i];
      z4[i] = make_float4(xv.x * qv.x, xv.y * qv.y, xv.z * qv.z, xv.w * qv.w);
    }
    __syncthreads();
    for (int q = 0; q < F0; ++q) {
      float4 zv = z4[(q << 2) + dd];
      int p = f * F0 + q;
      float ww[4] = {w0[(h0 + 0) * P0_ + p], w0[(h0 + 1) * P0_ + p],
                     w0[(h0 + 2) * P0_ + p], w0[(h0 + 3) * P0_ + p]};
      float zz[4] = {zv.x, zv.y, zv.z, zv.w};
#pragma unroll
      for (int hi = 0; hi < 4; ++hi)
#pragma unroll
        for (int di = 0; di < 4; ++di) acc[hi][di] += ww[hi] * zz[di];
    }
    __syncthreads();
  }
#pragma unroll
  for (int hi = 0; hi < 4; ++hi)
    h1s4[(h0 + hi) * 4 + dd] = make_float4(acc[hi][0], acc[hi][1], acc[hi][2], acc[hi][3]);
  __syncthreads();
  {
    float4 a0 = h1s4[tid * 4 + 0], a1 = h1s4[tid * 4 + 1];
    float4 a2 = h1s4[tid * 4 + 2], a3 = h1s4[tid * 4 + 3];
    out[(size_t)b * 256 + tid] = (a0.x + a0.y + a0.z + a0.w) + (a1.x + a1.y + a1.z + a1.w) +
                                 (a2.x + a2.y + a2.z + a2.w) + (a3.x + a3.y + a3.z + a3.w);
  }
#pragma unroll
  for (int i = 0; i < 4; ++i)
#pragma unroll
    for (int j = 0; j < 4; ++j) acc[i][j] = 0.f;
  for (int f = 0; f < F0; ++f) {
    for (int i = tid; i < H_ * D_ / 4; i += 128) {
      float4 xv = xs4[(f << 2) + (i & 3)], hv = h1s4[i];
      z4[i] = make_float4(xv.x * hv.x, xv.y * hv.y, xv.z * hv.z, xv.w * hv.w);
    }
    __syncthreads();
    for (int q = 0; q < H_; ++q) {
      float4 zv = z4[(q << 2) + dd];
      int p = f * H_ + q;
      float ww[4] = {w1[(h0 + 0) * P1_ + p], w1[(h0 + 1) * P1_ + p],
                     w1[(h0 + 2) * P1_ + p], w1[(h0 + 3) * P1_ + p]};
      float zz[4] = {zv.x, zv.y, zv.z, zv.w};
#pragma unroll
      for (int hi = 0; hi < 4; ++hi)
#pragma unroll
        for (int di = 0; di < 4; ++di) acc[hi][di] += ww[hi] * zz[di];
    }
    __syncthreads();
  }
#pragma unroll
  for (int hi = 0; hi < 4; ++hi)
    z4[(h0 + hi) * 4 + dd] = make_float4(acc[hi][0], acc[hi][1], acc[hi][2], acc[hi][3]);
  __syncthreads();
  {
    float4 a0 = z4[tid * 4 + 0], a1 = z4[tid * 4 + 1];
    float4 a2 = z4[tid * 4 + 2], a3 = z4[tid * 4 + 3];
    out[(size_t)b * 256 + 128 + tid] = (a0.x + a0.y + a0.z + a0.w) + (a1.x + a1.y + a1.z + a1.w) +
                                       (a2.x + a2.y + a2.z + a2.w) + (a3.x + a3.y + a3.z + a3.w);
  }
}

extern "C" void kernel_launch(void* const* d_in, const int* in_sizes, int n_in,
                              void* d_out, int out_size, void* d_ws, size_t ws_size,
                              hipStream_t stream) {
  const float* x  = (const float*)d_in[0];
  const float* w0 = (const float*)d_in[1];
  const float* w1 = (const float*)d_in[2];
  float* out = (float*)d_out;

  const size_t nfr   = (size_t)(NF1 + NF2) * 64;            // frag*lane count
  const size_t wbytes = nfr * sizeof(short8);               // ~1.92 MB
  const size_t ubytes = (size_t)2048 * P1_ * sizeof(unsigned short);  // ~20.4 MB

  if (ws_size >= wbytes + ubytes) {
    short8* wA1 = (short8*)d_ws;
    short8* wA2 = wA1 + (size_t)NF1 * 64;
    unsigned short* U = (unsigned short*)(wA2 + (size_t)NF2 * 64);
    hipMemsetAsync(d_out, 0, (size_t)out_size * sizeof(float), stream);
    pack_w_kernel<<<(int)((nfr + 255) / 256), 256, 0, stream>>>(w0, w1, wA1, wA2);
    cin_phaseA<<<256, 512, 0, stream>>>(x, wA1, out, U);
    cin_phaseB<<<256, 256, 0, stream>>>(U, wA2, out);
  } else if (ws_size >= wbytes) {
    short8* wA1 = (short8*)d_ws;
    short8* wA2 = wA1 + (size_t)NF1 * 64;
    pack_w_kernel<<<(int)((nfr + 255) / 256), 256, 0, stream>>>(w0, w1, wA1, wA2);
    cin_mfma_g4<<<512, 256, 0, stream>>>(x, wA1, wA2, out);
  } else {
    cin_fused_fallback<<<2048, 128, 0, stream>>>(x, w0, w1, out);
  }
}

// Round 5
// 95.542 us; speedup vs baseline: 1.5761x; 1.5761x over previous
//
#include <hip/hip_runtime.h>

// CIN fully fused, d-contraction-first:
//   out1[b,h] = sum_d h1[b,h,d];  h1 = sum_{f,q} W0[h,fq] x[b,f,d] x[b,q,d]
//   out2[b,h] = sum_p W1[h,p] U[b,p];  U[b,(f,q)] = sum_d x[b,f,d] h1[b,q,d]
// One kernel, 256 blocks x 512 thr (G=8 batches/block, 1 block/CU, 132KB LDS):
//   phase 1: layer-1 K-loop (wave = m-tile, scale-free, per-f fp32 epilogue)
//   phase 2: h1 -> LDS bf16; out1; U built via MFMA (wave = g) into LDS Ub
//            stored directly in out2 B-frag layout
//   phase 3: out2 GEMM: 156 chunks, W1 frag stream from L2 (1.25MB/block,
//            ~56 B/cyc/CU bound), 4 acc chains, 4-deep prefetch. No atomics.

#define F0   39
#define D_   16
#define H_   128
#define P0_  1521
#define P1_  4992
#define G8   8
#define NF1  (F0 * 2 * 8)   // 624 layer-1 A-frags
#define NF2  (F0 * 4 * 8)   // 1248 W1 A-frags
#define NC2  (F0 * 4)       // 156 out2 k-chunks
#define UBC  264            // Ub shorts per chunk (256 used + 8 pad)
#define SROW 138            // S_bf row stride in shorts (128 used + 10 pad)

typedef __attribute__((ext_vector_type(8))) short   short8;
typedef __attribute__((ext_vector_type(8))) __bf16  bf16x8;
typedef __attribute__((ext_vector_type(4))) float   floatx4;

__device__ __forceinline__ unsigned short bf16rne(float f) {
  unsigned int u = __float_as_uint(f);
  u += 0x7FFFu + ((u >> 16) & 1u);
  return (unsigned short)(u >> 16);
}

__device__ __forceinline__ floatx4 mfma16(short8 a, short8 b, floatx4 c) {
  return __builtin_amdgcn_mfma_f32_16x16x32_bf16(
      __builtin_bit_cast(bf16x8, a), __builtin_bit_cast(bf16x8, b), c, 0, 0, 0);
}

// ---------- pack W into MFMA A-frag order (verified R3/R4) ----------
__global__ __launch_bounds__(256) void pack_w_kernel(const float* __restrict__ w0,
                                                     const float* __restrict__ w1,
                                                     short8* __restrict__ wA1,
                                                     short8* __restrict__ wA2) {
  int id = blockIdx.x * 256 + threadIdx.x;
  union { short8 v; unsigned short e[8]; } pk;
  if (id < NF1 * 64) {
    int lane = id & 63, frag = id >> 6;
    int t = frag & 7, s = (frag >> 3) & 1, f = frag >> 4;
    int m = t * 16 + (lane & 15);
    int qb = s * 32 + (lane >> 4) * 8;
#pragma unroll
    for (int j = 0; j < 8; ++j) {
      int q = qb + j;
      float v = (q < F0) ? w0[(size_t)m * P0_ + f * F0 + q] : 0.f;
      pk.e[j] = bf16rne(v);
    }
    wA1[frag * 64 + lane] = pk.v;
  } else if (id < (NF1 + NF2) * 64) {
    int u = id - NF1 * 64;
    int lane = u & 63, frag = u >> 6;
    int t = frag & 7, s = (frag >> 3) & 3, f = frag >> 5;
    int m = t * 16 + (lane & 15);
    int pb = f * 128 + s * 32 + (lane >> 4) * 8;
#pragma unroll
    for (int j = 0; j < 8; ++j) pk.e[j] = bf16rne(w1[(size_t)m * P1_ + pb + j]);
    wA2[frag * 64 + lane] = pk.v;
  }
}

// ---------- fused main kernel ----------
__global__ __launch_bounds__(512) void cin_fused(const float* __restrict__ x,
                                                 const short8* __restrict__ wA1,
                                                 const short8* __restrict__ wA2,
                                                 float* __restrict__ out) {
  // LDS map: [0,19968) xs fp32 | [19968,55296) S_bf | [55296,...) xTb then Ub
  __shared__ __align__(16) char smem[19968 + 128 * SROW * 2 + NC2 * UBC * 2];
  float (*xs)[F0][D_]   = (float (*)[F0][D_])smem;
  unsigned short* S_bf  = (unsigned short*)(smem + 19968);          // [128][SROW]
  unsigned short* xTb   = (unsigned short*)(smem + 55296);          // dead before Ub
  unsigned short* Ub    = (unsigned short*)(smem + 55296);          // [NC2][4][8][8]+pad

  const int tid  = threadIdx.x;
  const int lane = tid & 63;
  const int wv   = tid >> 6;      // 8 waves
  const int col  = lane & 15;
  const int quad = lane >> 4;
  const int b0   = blockIdx.x * G8;
  const floatx4 zf4 = {0.f, 0.f, 0.f, 0.f};

  // ---- stage x (coalesced float4) ----
  {
    const float4* xg = (const float4*)(x + (size_t)b0 * (F0 * D_));
    float4* xl = (float4*)smem;
    for (int i = tid; i < G8 * F0 * D_ / 4; i += 512) xl[i] = xg[i];
  }
  __syncthreads();

  // ---- xTb[g][q8][d][j] = bf16(x[g][q8*8+j][d]), zero-pad q>=39 ----
  for (int i = tid; i < G8 * 8 * D_; i += 512) {
    int d = i & 15, q8 = (i >> 4) & 7, g = i >> 7;
    union { short8 v; unsigned short e[8]; } pk;
#pragma unroll
    for (int j = 0; j < 8; ++j) {
      int q = q8 * 8 + j;
      pk.e[j] = (q < F0) ? bf16rne(xs[g][q][d]) : (unsigned short)0;
    }
    *(short8*)&xTb[(size_t)i * 8] = pk.v;
  }
  __syncthreads();

  // layer-1 B-frags (f-invariant), cached in VGPRs
  short8 bx[2][G8];
#pragma unroll
  for (int s = 0; s < 2; ++s)
#pragma unroll
    for (int g = 0; g < G8; ++g)
      bx[s][g] = *(const short8*)&xTb[(size_t)(((g * 8 + s * 4 + quad) * 16) + col) * 8];

  floatx4 acc2[G8];
#pragma unroll
  for (int g = 0; g < G8; ++g) acc2[g] = zf4;

  // ===== phase 1: layer 1 (wave = m-tile t = wv), double-buffered A-frags =====
  {
    const int t = wv;
    short8 a0 = wA1[(size_t)(0 * 8 + t) * 64 + lane];
    short8 a1 = wA1[(size_t)(1 * 8 + t) * 64 + lane];
    for (int f = 0; f < F0; ++f) {
      int fn = (f + 1 < F0) ? f + 1 : f;
      short8 na0 = wA1[(size_t)((fn * 2 + 0) * 8 + t) * 64 + lane];
      short8 na1 = wA1[(size_t)((fn * 2 + 1) * 8 + t) * 64 + lane];
      float sx[G8];
#pragma unroll
      for (int g = 0; g < G8; ++g) sx[g] = xs[g][f][col];
#pragma unroll
      for (int g = 0; g < G8; ++g) {
        floatx4 acf = mfma16(a0, bx[0][g], zf4);
        acf = mfma16(a1, bx[1][g], acf);
#pragma unroll
        for (int r = 0; r < 4; ++r) acc2[g][r] += acf[r] * sx[g];
      }
      a0 = na0; a1 = na1;
    }
    // h1 -> S_bf (bf16).  Row = h, col = g*16+d.  (xTb now dead; Ub aliases it.)
#pragma unroll
    for (int g = 0; g < G8; ++g)
#pragma unroll
      for (int r = 0; r < 4; ++r)
        S_bf[(size_t)((t * 16 + quad * 4 + r) * SROW) + g * 16 + col] =
            bf16rne(acc2[g][r]);
  }
  __syncthreads();

  // ===== phase 2a: out1[b,h] = sum_d h1 =====
  for (int i = tid; i < G8 * H_; i += 512) {
    int h = i & 127, g = i >> 7;
    const unsigned short* sp = &S_bf[(size_t)h * SROW + g * 16];
    float sum = 0.f;
#pragma unroll
    for (int d = 0; d < D_; ++d)
      sum += __uint_as_float((unsigned int)sp[d] << 16);
    out[(size_t)(b0 + g) * 256 + h] = sum;
  }

  // ===== phase 2b: U[g,(f,q)] = sum_d x[g,f,d] h1[g,q,d]  (wave = g = wv) =====
  // MFMA: A[m=f][k=d], B[n=q][k=d] -> C[m=f][n=q]; scatter to Ub in B-frag layout
  {
    const int g = wv;
    short8 af[3];
#pragma unroll
    for (int ft = 0; ft < 3; ++ft) {
      union { short8 v; unsigned short e[8]; } pk;
      int f = ft * 16 + col;
      if (quad < 2 && f < F0) {
        const float* xp = &xs[g][f][quad * 8];
#pragma unroll
        for (int j = 0; j < 8; ++j) pk.e[j] = bf16rne(xp[j]);
      } else {
#pragma unroll
        for (int j = 0; j < 8; ++j) pk.e[j] = 0;
      }
      af[ft] = pk.v;
    }
#pragma unroll
    for (int qt = 0; qt < 8; ++qt) {
      union { short8 v; unsigned short e[8]; } pk;
      int q = qt * 16 + col;
      if (quad < 2) {
        const unsigned short* sp = &S_bf[(size_t)q * SROW + g * 16 + quad * 8];
#pragma unroll
        for (int j = 0; j < 8; ++j) pk.e[j] = sp[j];   // already bf16
      } else {
#pragma unroll
        for (int j = 0; j < 8; ++j) pk.e[j] = 0;
      }
      short8 bq = pk.v;
#pragma unroll
      for (int ft = 0; ft < 3; ++ft) {
        floatx4 c2 = mfma16(af[ft], bq, zf4);
#pragma unroll
        for (int r = 0; r < 4; ++r) {
          int f = ft * 16 + quad * 4 + r;
          if (f < F0) {
            int c  = f * 4 + (qt >> 1);              // k-chunk = p/32
            int qb = (qt * 2 + (col >> 3)) & 3;      // (p%32)/8
            Ub[(size_t)c * UBC + qb * 64 + g * 8 + (col & 7)] = bf16rne(c2[r]);
          }
        }
      }
    }
  }
  __syncthreads();

  // ===== phase 3: out2[h, g] = sum_c W1frag(c) x Ufrag(c)  (wave = m-tile t) =====
  {
    const int t = wv;
    const short8 zero8 = {0, 0, 0, 0, 0, 0, 0, 0};
    floatx4 aco[4];
#pragma unroll
    for (int i = 0; i < 4; ++i) aco[i] = zf4;
    short8 aW[4];
#pragma unroll
    for (int i = 0; i < 4; ++i) aW[i] = wA2[(size_t)(i * 8 + t) * 64 + lane];
    for (int cb = 0; cb < F0; ++cb) {
      int cn = (cb + 1 < F0) ? (cb + 1) * 4 : cb * 4;
      short8 nx[4];
#pragma unroll
      for (int i = 0; i < 4; ++i) nx[i] = wA2[(size_t)((cn + i) * 8 + t) * 64 + lane];
#pragma unroll
      for (int i = 0; i < 4; ++i) {
        int c = cb * 4 + i;
        short8 bU = (col < 8)
            ? *(const short8*)&Ub[(size_t)c * UBC + quad * 64 + (col & 7) * 8]
            : zero8;
        aco[i] = mfma16(aW[i], bU, aco[i]);
      }
#pragma unroll
      for (int i = 0; i < 4; ++i) aW[i] = nx[i];
    }
    if (col < 8) {
#pragma unroll
      for (int r = 0; r < 4; ++r) {
        float v = (aco[0][r] + aco[1][r]) + (aco[2][r] + aco[3][r]);
        out[(size_t)(b0 + col) * 256 + 128 + t * 16 + quad * 4 + r] = v;
      }
    }
  }
}

// ---------- fp32 last-resort fallback ----------
__global__ __launch_bounds__(128) void cin_fused_fallback(const float* __restrict__ x,
                                                          const float* __restrict__ w0,
                                                          const float* __restrict__ w1,
                                                          float* __restrict__ out) {
  __shared__ float4 xs4[F0 * D_ / 4];
  __shared__ float4 h1s4[H_ * D_ / 4];
  __shared__ float4 z4[H_ * D_ / 4];
  const int tid = threadIdx.x;
  const int b = blockIdx.x;
  const int hh = tid >> 2, dd = tid & 3, h0 = hh << 2;
  {
    const float4* xg = (const float4*)(x + (size_t)b * (F0 * D_));
    for (int i = tid; i < F0 * D_ / 4; i += 128) xs4[i] = xg[i];
  }
  __syncthreads();
  float acc[4][4];
#pragma unroll
  for (int i = 0; i < 4; ++i)
#pragma unroll
    for (int j = 0; j < 4; ++j) acc[i][j] = 0.f;
  for (int f = 0; f < F0; ++f) {
    for (int i = tid; i < F0 * D_ / 4; i += 128) {
      float4 xv = xs4[(f << 2) + (i & 3)], qv = xs4[i];
      z4[i] = make_float4(xv.x * qv.x, xv.y * qv.y, xv.z * qv.z, xv.w * qv.w);
    }
    __syncthreads();
    for (int q = 0; q < F0; ++q) {
      float4 zv = z4[(q << 2) + dd];
      int p = f * F0 + q;
      float ww[4] = {w0[(h0 + 0) * P0_ + p], w0[(h0 + 1) * P0_ + p],
                     w0[(h0 + 2) * P0_ + p], w0[(h0 + 3) * P0_ + p]};
      float zz[4] = {zv.x, zv.y, zv.z, zv.w};
#pragma unroll
      for (int hi = 0; hi < 4; ++hi)
#pragma unroll
        for (int di = 0; di < 4; ++di) acc[hi][di] += ww[hi] * zz[di];
    }
    __syncthreads();
  }
#pragma unroll
  for (int hi = 0; hi < 4; ++hi)
    h1s4[(h0 + hi) * 4 + dd] = make_float4(acc[hi][0], acc[hi][1], acc[hi][2], acc[hi][3]);
  __syncthreads();
  {
    float4 a0 = h1s4[tid * 4 + 0], a1 = h1s4[tid * 4 + 1];
    float4 a2 = h1s4[tid * 4 + 2], a3 = h1s4[tid * 4 + 3];
    out[(size_t)b * 256 + tid] = (a0.x + a0.y + a0.z + a0.w) + (a1.x + a1.y + a1.z + a1.w) +
                                 (a2.x + a2.y + a2.z + a2.w) + (a3.x + a3.y + a3.z + a3.w);
  }
#pragma unroll
  for (int i = 0; i < 4; ++i)
#pragma unroll
    for (int j = 0; j < 4; ++j) acc[i][j] = 0.f;
  for (int f = 0; f < F0; ++f) {
    for (int i = tid; i < H_ * D_ / 4; i += 128) {
      float4 xv = xs4[(f << 2) + (i & 3)], hv = h1s4[i];
      z4[i] = make_float4(xv.x * hv.x, xv.y * hv.y, xv.z * hv.z, xv.w * hv.w);
    }
    __syncthreads();
    for (int q = 0; q < H_; ++q) {
      float4 zv = z4[(q << 2) + dd];
      int p = f * H_ + q;
      float ww[4] = {w1[(h0 + 0) * P1_ + p], w1[(h0 + 1) * P1_ + p],
                     w1[(h0 + 2) * P1_ + p], w1[(h0 + 3) * P1_ + p]};
      float zz[4] = {zv.x, zv.y, zv.z, zv.w};
#pragma unroll
      for (int hi = 0; hi < 4; ++hi)
#pragma unroll
        for (int di = 0; di < 4; ++di) acc[hi][di] += ww[hi] * zz[di];
    }
    __syncthreads();
  }
#pragma unroll
  for (int hi = 0; hi < 4; ++hi)
    z4[(h0 + hi) * 4 + dd] = make_float4(acc[hi][0], acc[hi][1], acc[hi][2], acc[hi][3]);
  __syncthreads();
  {
    float4 a0 = z4[tid * 4 + 0], a1 = z4[tid * 4 + 1];
    float4 a2 = z4[tid * 4 + 2], a3 = z4[tid * 4 + 3];
    out[(size_t)b * 256 + 128 + tid] = (a0.x + a0.y + a0.z + a0.w) + (a1.x + a1.y + a1.z + a1.w) +
                                       (a2.x + a2.y + a2.z + a2.w) + (a3.x + a3.y + a3.z + a3.w);
  }
}

extern "C" void kernel_launch(void* const* d_in, const int* in_sizes, int n_in,
                              void* d_out, int out_size, void* d_ws, size_t ws_size,
                              hipStream_t stream) {
  const float* x  = (const float*)d_in[0];
  const float* w0 = (const float*)d_in[1];
  const float* w1 = (const float*)d_in[2];
  float* out = (float*)d_out;

  const size_t nfr    = (size_t)(NF1 + NF2) * 64;   // 119808 (frag,lane) pairs
  const size_t wbytes = nfr * sizeof(short8);       // ~1.92 MB

  if (ws_size >= wbytes) {
    short8* wA1 = (short8*)d_ws;
    short8* wA2 = wA1 + (size_t)NF1 * 64;
    pack_w_kernel<<<(int)((nfr + 255) / 256), 256, 0, stream>>>(w0, w1, wA1, wA2);
    cin_fused<<<256, 512, 0, stream>>>(x, wA1, wA2, out);
  } else {
    cin_fused_fallback<<<2048, 128, 0, stream>>>(x, w0, w1, out);
  }
}